// Round 5
// baseline (365.046 us; speedup 1.0000x reference)
//
#include <hip/hip_runtime.h>
#include <math.h>

constexpr int NPGc  = 128;     // nodes per graph (layer 1)
constexpr int NG    = 512;     // graphs
constexpr int EPGc  = 2048;    // edges per graph
constexpr int ETOT  = 1048576; // total edges
constexpr int IND   = 11;
constexpr int HIDc  = 32;
constexpr int FD    = 128;     // HEADS*HID
constexpr int K1c   = 103;
constexpr int K2c   = 83;
constexpr int NN    = NG * NPGc;
constexpr int N2c   = NG * K1c;

__device__ __forceinline__ float lrelu(float x){ return fmaxf(x, 0.2f*x); }

// order-preserving float<->uint for atomicMax
__device__ __forceinline__ unsigned flipF(float f){
    unsigned u = __float_as_uint(f);
    return u ^ (unsigned)(((int)u >> 31) | 0x80000000);
}
__device__ __forceinline__ float unflipF(unsigned u){
    unsigned m = ((u >> 31) - 1u) | 0x80000000u;
    return __uint_as_float(u ^ m);
}

// ---- fused proj + GAT, one block per (graph, head) ----
template<int NNODE, int KIN, bool REMAP>
__global__ __launch_bounds__(256) void k_gat(
    const float* __restrict__ xin, const float* __restrict__ Wg,
    const float* __restrict__ avs, const float* __restrict__ avd,
    const int* __restrict__ ei, const int* __restrict__ rankv,
    const float* __restrict__ bias, float* __restrict__ outp)
{
    int g = blockIdx.x, h = blockIdx.y, t = threadIdx.x;
    __shared__ __align__(16) float xpL[NNODE * 36];   // pad 36: conflict-free octet b128 gather
    __shared__ __align__(16) float xF[NNODE * KIN];   // staged input slice
    __shared__ unsigned char bucket[EPGc];
    __shared__ float asL[NNODE], adL[NNODE], sDen[NNODE];
    __shared__ unsigned maxAsU[NNODE];                // reused as mLn (float) after phase 3
    __shared__ int cnt[128], offA[129], curA[128];
    __shared__ float WL[KIN * 32];
    __shared__ float avsL[32], avdL[32], bL[32];
    __shared__ signed char rmap[REMAP ? NPGc : 1];

    float* mLn = (float*)maxAsU;

    // ---- phase 0: stage x slice, weight column, head vectors ----
    {
        const float* xg = xin + (size_t)g * NNODE * KIN;
        if constexpr ((KIN & 3) == 0) {
            for (int i = t; i < NNODE * (KIN/4); i += 256)
                ((float4*)xF)[i] = ((const float4*)xg)[i];
        } else {
            for (int i = t; i < NNODE * KIN; i += 256) xF[i] = xg[i];
        }
    }
    for (int i = t; i < KIN * 32; i += 256) { int k = i >> 5, c = i & 31; WL[i] = Wg[k*FD + h*32 + c]; }
    if (t < 32) { avsL[t] = avs[h*32 + t]; avdL[t] = avd[h*32 + t]; bL[t] = bias[h*32 + t]; }
    if (t < 128) cnt[t] = 0;
    if constexpr (REMAP) { if (t < NPGc) rmap[t] = (signed char)rankv[g*NPGc + t]; }
    __syncthreads();

    // ---- phase 1: xp = xF @ WL -> xpL ----
    for (int p = t; p < NNODE * 32; p += 256) {
        int n = p >> 5, c = p & 31;
        const float* xr = xF + n * KIN;
        float acc = 0.f;
        #pragma unroll
        for (int k = 0; k < KIN; k++) acc = fmaf(xr[k], WL[k*32 + c], acc);
        xpL[n*36 + c] = acc;
    }
    __syncthreads();

    // ---- phase 1b: as/ad = xp . av (octet partials + shfl butterfly) ----
    for (int p = t; p < NNODE * 8; p += 256) {
        int n = p >> 3, jo = p & 7;
        const float* xr = xpL + n*36 + jo*4;
        float s = 0.f, d = 0.f;
        #pragma unroll
        for (int jj = 0; jj < 4; jj++) {
            float v = xr[jj];
            s = fmaf(v, avsL[jo*4 + jj], s);
            d = fmaf(v, avdL[jo*4 + jj], d);
        }
        s += __shfl_xor(s, 1); d += __shfl_xor(d, 1);
        s += __shfl_xor(s, 2); d += __shfl_xor(d, 2);
        s += __shfl_xor(s, 4); d += __shfl_xor(d, 4);
        if (jo == 0) { asL[n] = s; adL[n] = d; maxAsU[n] = flipF(s); }  // self seeds max
    }
    __syncthreads();

    // ---- phase 2: edges -> counts + per-dst max(as) (lrelu monotone => exact) ----
    const int* dstG = ei + ETOT + g * EPGc;
    int snR[8], dnR[8];
    #pragma unroll
    for (int q = 0; q < 8; q++) {
        int e = t + 256*q;
        int dO = dstG[e] - g * NPGc, s0 = e >> 4;     // src is structural: e/16
        if constexpr (REMAP) {
            int sn = rmap[s0], dn = rmap[dO];
            bool ok = (sn >= 0 && dn >= 0);
            snR[q] = ok ? sn : -1; dnR[q] = ok ? dn : -1;
        } else { snR[q] = s0; dnR[q] = dO; }
        if (dnR[q] >= 0) {
            atomicAdd(&cnt[dnR[q]], 1);
            atomicMax(&maxAsU[dnR[q]], flipF(asL[snR[q]]));
        }
    }
    __syncthreads();

    // ---- phase 3: wave0 scan -> offsets; waves 1-2: m + denom seed ----
    if (t < 64) {
        int c0 = cnt[2*t], c1 = cnt[2*t + 1], ps = c0 + c1, P = ps;
        #pragma unroll
        for (int dlt = 1; dlt < 64; dlt <<= 1) { int v = __shfl_up(P, dlt); if (t >= dlt) P += v; }
        int E0 = P - ps;
        offA[2*t] = E0; offA[2*t + 1] = E0 + c0;
        curA[2*t] = E0; curA[2*t + 1] = E0 + c0;
        if (t == 63) offA[128] = P;
    } else if (t < 64 + NNODE) {
        int n = t - 64;
        float m = lrelu(unflipF(maxAsU[n]) + adL[n]);  // exact segment max
        float ws = expf(lrelu(asL[n] + adL[n]) - m);
        sDen[n] = ws;
        mLn[n] = m;                                    // in-place over maxAsU
    }
    __syncthreads();

    // ---- phase 4: CSR scatter + denominator ----
    #pragma unroll
    for (int q = 0; q < 8; q++) {
        int dn = dnR[q];
        if (dn >= 0) {
            int sn = snR[q];
            float w = expf(lrelu(asL[sn] + adL[dn]) - mLn[dn]);
            int pos = atomicAdd(&curA[dn], 1);
            bucket[pos] = (unsigned char)sn;
            atomicAdd(&sDen[dn], w);
        }
    }
    __syncthreads();

    // ---- phase 5: aggregation, w recomputed inline, all LDS ----
    const float4* X4 = (const float4*)xpL;
    for (int p = t; p < NNODE * 8; p += 256) {
        int n = p >> 3, c4 = p & 7;
        float adn = adL[n], m = mLn[n];
        float w0 = expf(lrelu(asL[n] + adn) - m);
        float4 v = X4[n*9 + c4];
        float4 acc; acc.x = w0*v.x; acc.y = w0*v.y; acc.z = w0*v.z; acc.w = w0*v.w;
        int lo = offA[n], hi = offA[n + 1];
        for (int i = lo; i < hi; i++) {
            int sc = bucket[i];
            float w = expf(lrelu(asL[sc] + adn) - m);
            float4 u = X4[sc*9 + c4];
            acc.x = fmaf(w, u.x, acc.x); acc.y = fmaf(w, u.y, acc.y);
            acc.z = fmaf(w, u.z, acc.z); acc.w = fmaf(w, u.w, acc.w);
        }
        float inv = 1.f / (sDen[n] + 1e-16f);
        float4 r;
        r.x = fmaxf(fmaf(acc.x, inv, bL[c4*4 + 0]), 0.f);
        r.y = fmaxf(fmaf(acc.y, inv, bL[c4*4 + 1]), 0.f);
        r.z = fmaxf(fmaf(acc.z, inv, bL[c4*4 + 2]), 0.f);
        r.w = fmaxf(fmaf(acc.w, inv, bL[c4*4 + 3]), 0.f);
        *(float4*)(outp + (size_t)(g * NNODE + n) * FD + h*32 + c4*4) = r;
    }
}

// ---- linear 128->32: 32 rows/block, 4 rows/thread, W staged in LDS ----
__global__ __launch_bounds__(256) void k_lin(const float* __restrict__ in,
    const float* __restrict__ W, const float* __restrict__ b, float* __restrict__ outp)
{
    __shared__ float WtL[FD * HIDc];
    int t = threadIdx.x;
    for (int i = t; i < FD * HIDc; i += 256) WtL[i] = W[i];
    __syncthreads();
    int j = t & 31, rg = t >> 5;
    int r0 = blockIdx.x * 32 + rg * 4;
    const float* i0 = in + (size_t)r0 * FD;
    float bj = b[j];
    float a0 = bj, a1 = bj, a2 = bj, a3 = bj;
    for (int k4 = 0; k4 < 32; k4++) {
        float4 v0 = *(const float4*)(i0 + k4*4);
        float4 v1 = *(const float4*)(i0 + FD + k4*4);
        float4 v2 = *(const float4*)(i0 + 2*FD + k4*4);
        float4 v3 = *(const float4*)(i0 + 3*FD + k4*4);
        float w0 = WtL[(k4*4 + 0)*HIDc + j], w1 = WtL[(k4*4 + 1)*HIDc + j];
        float w2 = WtL[(k4*4 + 2)*HIDc + j], w3 = WtL[(k4*4 + 3)*HIDc + j];
        a0 = fmaf(v0.x, w0, a0); a0 = fmaf(v0.y, w1, a0); a0 = fmaf(v0.z, w2, a0); a0 = fmaf(v0.w, w3, a0);
        a1 = fmaf(v1.x, w0, a1); a1 = fmaf(v1.y, w1, a1); a1 = fmaf(v1.z, w2, a1); a1 = fmaf(v1.w, w3, a1);
        a2 = fmaf(v2.x, w0, a2); a2 = fmaf(v2.y, w1, a2); a2 = fmaf(v2.z, w2, a2); a2 = fmaf(v2.w, w3, a2);
        a3 = fmaf(v3.x, w0, a3); a3 = fmaf(v3.y, w1, a3); a3 = fmaf(v3.z, w2, a3); a3 = fmaf(v3.w, w3, a3);
    }
    size_t ob = (size_t)r0 * HIDc + j;
    outp[ob] = a0; outp[ob + 32] = a1; outp[ob + 64] = a2; outp[ob + 96] = a3;
}

// ---- top-k pool + readout, one graph per block ----
template<int NIN, int KEEP, bool FIRST>
__global__ __launch_bounds__(256) void k_pool(const float* __restrict__ ht,
    const float* __restrict__ pw, float* __restrict__ xnew, int* __restrict__ rankv,
    float* __restrict__ gfeat, const float* __restrict__ gprev)
{
    int g = blockIdx.x, t = threadIdx.x;
    __shared__ float htL[NIN * 33];
    __shared__ float scoreL[NIN], valL[NIN];
    __shared__ int rnkL[NIN];
    for (int i = t; i < NIN * 8; i += 256) {
        int n = i >> 3, q = i & 7;
        float4 v = *(const float4*)(ht + (size_t)(g*NIN + n)*HIDc + q*4);
        float* dst = htL + n*33 + q*4;
        dst[0] = v.x; dst[1] = v.y; dst[2] = v.z; dst[3] = v.w;
    }
    __syncthreads();
    float nrm; { float ss = 0.f; for (int k = 0; k < HIDc; k++) { float w = pw[k]; ss = fmaf(w, w, ss); } nrm = sqrtf(ss); }
    if (t < NIN) {
        float dot = 0.f;
        for (int k = 0; k < HIDc; k++) dot = fmaf(htL[t*33 + k], pw[k], dot);
        float val = tanhf(dot / nrm);
        scoreL[t] = val; valL[t] = val;
    }
    __syncthreads();
    if (t < NIN) {
        float si = scoreL[t]; int rank = 0;
        for (int q = 0; q < NIN; q++) {
            float sj = scoreL[q];
            rank += (sj > si || (sj == si && q < t)) ? 1 : 0;
        }
        rnkL[t] = (rank < KEEP) ? rank : -1;
        if (FIRST) rankv[g*NPGc + t] = rnkL[t];
    }
    __syncthreads();
    if (FIRST) {
        for (int p = t; p < NIN * 32; p += 256) {
            int n = p >> 5, jj = p & 31;
            int rk = rnkL[n];
            if (rk >= 0) xnew[((size_t)g*KEEP + rk)*HIDc + jj] = htL[n*33 + jj] * valL[n];
        }
    }
    if (t < HIDc) {
        float mx = -INFINITY, sm = 0.f;
        for (int n = 0; n < NIN; n++) {
            if (rnkL[n] >= 0) { float v = htL[n*33 + t] * valL[n]; mx = fmaxf(mx, v); sm += v; }
        }
        float mean = sm / (float)KEEP;
        if (FIRST) {
            gfeat[(size_t)g*64 + t]      = mx;
            gfeat[(size_t)g*64 + 32 + t] = mean;
        } else {
            gfeat[(size_t)g*64 + t]      = gprev[(size_t)g*64 + t] + mx;
            gfeat[(size_t)g*64 + 32 + t] = gprev[(size_t)g*64 + 32 + t] + mean;
        }
    }
}

// ---- MLP part A: block = (4 graphs, quarter of h2) ----
__global__ __launch_bounds__(256) void k_mlpA(const float* __restrict__ gsum,
    const float* __restrict__ W1, const float* __restrict__ b1,
    const float* __restrict__ W2, const float* __restrict__ b2,
    const float* __restrict__ W3, float* __restrict__ part)
{
    int gb = blockIdx.x, q = blockIdx.y, t = threadIdx.x;
    int g0 = gb * 4;
    __shared__ float gL[256];
    __shared__ float h1L[1024];
    __shared__ float4 red[256];
    gL[t] = gsum[(size_t)g0*64 + t];
    __syncthreads();
    float bv = b1[t];
    float a0 = bv, a1 = bv, a2 = bv, a3 = bv;
    #pragma unroll 4
    for (int k = 0; k < 64; k++) {
        float w = W1[k*256 + t];
        a0 = fmaf(gL[k], w, a0); a1 = fmaf(gL[64 + k], w, a1);
        a2 = fmaf(gL[128 + k], w, a2); a3 = fmaf(gL[192 + k], w, a3);
    }
    h1L[t] = fmaxf(a0, 0.f); h1L[256 + t] = fmaxf(a1, 0.f);
    h1L[512 + t] = fmaxf(a2, 0.f); h1L[768 + t] = fmaxf(a3, 0.f);
    __syncthreads();
    int o = q * 256 + t;
    float b2v = b2[o], w3 = W3[o];
    float c0 = b2v, c1 = b2v, c2 = b2v, c3 = b2v;
    const float* w2c = W2 + o;
    #pragma unroll 8
    for (int i = 0; i < 256; i++) {
        float w = w2c[(size_t)i * 1024];
        c0 = fmaf(h1L[i], w, c0); c1 = fmaf(h1L[256 + i], w, c1);
        c2 = fmaf(h1L[512 + i], w, c2); c3 = fmaf(h1L[768 + i], w, c3);
    }
    red[t] = make_float4(fmaxf(c0, 0.f)*w3, fmaxf(c1, 0.f)*w3, fmaxf(c2, 0.f)*w3, fmaxf(c3, 0.f)*w3);
    __syncthreads();
    for (int s = 128; s > 0; s >>= 1) {
        if (t < s) { float4 a = red[t], b = red[t + s]; a.x += b.x; a.y += b.y; a.z += b.z; a.w += b.w; red[t] = a; }
        __syncthreads();
    }
    if (t == 0) {
        float4 r = red[0];
        part[(size_t)(g0 + 0)*4 + q] = r.x;
        part[(size_t)(g0 + 1)*4 + q] = r.y;
        part[(size_t)(g0 + 2)*4 + q] = r.z;
        part[(size_t)(g0 + 3)*4 + q] = r.w;
    }
}

// ---- MLP part B: deterministic 4-way partial sum + bias ----
__global__ void k_mlpB(const float* __restrict__ part, const float* __restrict__ b3,
                       float* __restrict__ outp)
{
    int g = blockIdx.x * 256 + threadIdx.x;
    if (g < NG) {
        float4 p = ((const float4*)part)[g];
        outp[g] = ((p.x + p.y) + (p.z + p.w)) + b3[0];
    }
}

extern "C" void kernel_launch(void* const* d_in, const int* in_sizes, int n_in,
                              void* d_out, int out_size, void* d_ws, size_t ws_size,
                              hipStream_t stream)
{
    const float* x    = (const float*)d_in[0];
    const int*   ei   = (const int*)  d_in[1];
    const float* W_g1 = (const float*)d_in[4];
    const float* as1w = (const float*)d_in[5];
    const float* ad1w = (const float*)d_in[6];
    const float* b_g1 = (const float*)d_in[7];
    const float* W_t1 = (const float*)d_in[8];
    const float* b_t1 = (const float*)d_in[9];
    const float* pw1  = (const float*)d_in[10];
    const float* W_g2 = (const float*)d_in[11];
    const float* as2w = (const float*)d_in[12];
    const float* ad2w = (const float*)d_in[13];
    const float* b_g2 = (const float*)d_in[14];
    const float* W_t2 = (const float*)d_in[15];
    const float* b_t2 = (const float*)d_in[16];
    const float* pw2  = (const float*)d_in[17];
    const float* W_l1 = (const float*)d_in[18];
    const float* b_l1 = (const float*)d_in[19];
    const float* W_l2 = (const float*)d_in[20];
    const float* b_l2 = (const float*)d_in[21];
    const float* W_l3 = (const float*)d_in[22];
    const float* b_l3 = (const float*)d_in[23];
    float* out = (float*)d_out;

    char* ws = (char*)d_ws;
    size_t off = 0;
    auto alloc = [&](size_t elems) -> float* {
        float* p = (float*)(ws + off);
        off += ((elems * 4 + 255) / 256) * 256;
        return p;
    };
    float* hg1  = alloc((size_t)NN * FD);     // reused as hg2 (dead after k_lin layer1)
    float* ht1  = alloc((size_t)NN * HIDc);   // reused as ht2 (dead after k_pool layer1)
    float* x2   = alloc((size_t)N2c * HIDc);
    int*   rank1= (int*)alloc((size_t)NN);
    float* g1   = alloc((size_t)NG * 64);
    float* gsum = alloc((size_t)NG * 64);
    float* part = alloc((size_t)NG * 4);
    float* hg2 = hg1;
    float* ht2 = ht1;

    k_gat<NPGc, IND, false><<<dim3(NG, 4), 256, 0, stream>>>(
        x, W_g1, as1w, ad1w, ei, nullptr, b_g1, hg1);
    k_lin<<<NN/32, 256, 0, stream>>>(hg1, W_t1, b_t1, ht1);
    k_pool<NPGc, K1c, true><<<NG, 256, 0, stream>>>(
        ht1, pw1, x2, rank1, g1, nullptr);

    k_gat<K1c, HIDc, true><<<dim3(NG, 4), 256, 0, stream>>>(
        x2, W_g2, as2w, ad2w, ei, rank1, b_g2, hg2);
    k_lin<<<N2c/32, 256, 0, stream>>>(hg2, W_t2, b_t2, ht2);
    k_pool<K1c, K2c, false><<<NG, 256, 0, stream>>>(
        ht2, pw2, nullptr, nullptr, gsum, g1);

    k_mlpA<<<dim3(NG/4, 4), 256, 0, stream>>>(gsum, W_l1, b_l1, W_l2, b_l2, W_l3, part);
    k_mlpB<<<2, 256, 0, stream>>>(part, b_l3, out);
}

// Round 6
// 329.381 us; speedup vs baseline: 1.1083x; 1.1083x over previous
//
#include <hip/hip_runtime.h>
#include <math.h>

constexpr int NPGc  = 128;     // nodes per graph (layer 1)
constexpr int NG    = 512;     // graphs
constexpr int EPGc  = 2048;    // edges per graph
constexpr int ETOT  = 1048576; // total edges
constexpr int IND   = 11;
constexpr int HIDc  = 32;
constexpr int FD    = 128;     // HEADS*HID
constexpr int K1c   = 103;
constexpr int K2c   = 83;
constexpr int NN    = NG * NPGc;
constexpr int N2c   = NG * K1c;

__device__ __forceinline__ float lrelu(float x){ return fmaxf(x, 0.2f*x); }

// ---- fold attention vectors through Wg: Ws[k][h] = sum_j Wg[k][h*32+j]*av[h*32+j]
template<int KIN>
__device__ void foldDev(const float* __restrict__ Wg, const float* __restrict__ avs,
                        const float* __restrict__ avd, float* __restrict__ S, float* __restrict__ D, int t)
{
    if (t < KIN * 4) {
        int k = t >> 2, h = t & 3;
        float s = 0.f, d = 0.f;
        for (int j = 0; j < HIDc; j++) {
            float w = Wg[k*FD + h*HIDc + j];
            s = fmaf(w, avs[h*HIDc + j], s);
            d = fmaf(w, avd[h*HIDc + j], d);
        }
        S[t] = s; D[t] = d;
    }
}
__global__ void k_fold2(const float* W1, const float* s1, const float* d1, float* S1, float* D1,
                        const float* W2, const float* s2, const float* d2, float* S2, float* D2)
{
    if (blockIdx.x == 0) foldDev<IND>(W1, s1, d1, S1, D1, threadIdx.x);
    else                 foldDev<HIDc>(W2, s2, d2, S2, D2, threadIdx.x);
}

// ---- CSR build, once per graph (head-independent) ----
// csrOff: NG x 132 ints; csrSB: NG x 2048 uchar (src id per slot)
template<bool REMAP>
__global__ __launch_bounds__(256) void k_csr(const int* __restrict__ ei, const int* __restrict__ rankv,
                                             int* __restrict__ csrOff, unsigned char* __restrict__ csrSB,
                                             int nnode)
{
    int g = blockIdx.x, t = threadIdx.x;
    __shared__ int cnt[128], cur[128], offL[129];
    __shared__ unsigned char sbL[EPGc];
    __shared__ signed char rmap[NPGc];
    if (t < 128) cnt[t] = 0;
    if constexpr (REMAP) { if (t < NPGc) rmap[t] = (signed char)rankv[g*NPGc + t]; }
    __syncthreads();
    const int* dstG = ei + ETOT + g * EPGc;
    int sn[8], dn[8];
    #pragma unroll
    for (int q = 0; q < 8; q++) {
        int e = t + 256*q;
        int dO = dstG[e] - g * NPGc, s0 = e >> 4;    // src is structural: e/16
        if constexpr (REMAP) {
            int s = rmap[s0], d = rmap[dO];
            bool ok = (s >= 0 && d >= 0);
            sn[q] = s; dn[q] = ok ? d : -1;
        } else { sn[q] = s0; dn[q] = dO; }
        if (dn[q] >= 0) atomicAdd(&cnt[dn[q]], 1);
    }
    __syncthreads();
    if (t < 64) {
        int c0 = cnt[2*t], c1 = cnt[2*t + 1], ps = c0 + c1, P = ps;
        #pragma unroll
        for (int dlt = 1; dlt < 64; dlt <<= 1) { int v = __shfl_up(P, dlt); if (t >= dlt) P += v; }
        int E0 = P - ps;
        offL[2*t] = E0; offL[2*t + 1] = E0 + c0;
        cur[2*t] = E0; cur[2*t + 1] = E0 + c0;
        if (t == 63) offL[128] = P;
    }
    __syncthreads();
    #pragma unroll
    for (int q = 0; q < 8; q++) {
        if (dn[q] >= 0) { int pos = atomicAdd(&cur[dn[q]], 1); sbL[pos] = (unsigned char)sn[q]; }
    }
    __syncthreads();
    if (t < 128) ((int4*)(csrSB + (size_t)g * EPGc))[t] = ((const int4*)sbL)[t];
    if (t <= nnode) csrOff[g*132 + t] = offL[t];
}

// ---- fused proj + GAT, one block per (graph, head); CSR pre-built ----
template<int NNODE, int KIN>
__global__ __launch_bounds__(256) void k_gat(
    const float* __restrict__ xin, const float* __restrict__ Wg,
    const float* __restrict__ WsS, const float* __restrict__ WsD,
    const int* __restrict__ csrOff, const unsigned char* __restrict__ csrSB,
    const float* __restrict__ bias, float* __restrict__ outp)
{
    int g = blockIdx.x, h = blockIdx.y, t = threadIdx.x;
    constexpr int UN = (NNODE*KIN > EPGc ? NNODE*KIN : EPGc);
    __shared__ __align__(16) float xpL[NNODE * 36];   // pad 36: conflict-free octet b128 gather
    __shared__ __align__(16) float uni[UN];           // phase<=1: xF staged input; phase>=2: wE
    __shared__ __align__(16) unsigned char sbL[EPGc];
    __shared__ float asL[NNODE], adL[NNODE], mM[NNODE], sfW[NNODE], sDen[NNODE];
    __shared__ int offL[NNODE + 1];
    __shared__ float WL[KIN * 32];
    __shared__ float WsSL[KIN], WsDL[KIN], bL[32];

    float* xF  = uni;
    float* wEL = uni;

    // ---- phase 0: stage x slice, weights, CSR ----
    {
        const float* xg = xin + (size_t)g * NNODE * KIN;
        if constexpr ((KIN & 3) == 0) {
            for (int i = t; i < NNODE * (KIN/4); i += 256)
                ((float4*)xF)[i] = ((const float4*)xg)[i];
        } else {
            for (int i = t; i < NNODE * KIN; i += 256) xF[i] = xg[i];
        }
    }
    for (int i = t; i < KIN * 32; i += 256) { int k = i >> 5, c = i & 31; WL[i] = Wg[k*FD + h*32 + c]; }
    if (t < KIN) { WsSL[t] = WsS[t*4 + h]; WsDL[t] = WsD[t*4 + h]; }
    if (t < 32) bL[t] = bias[h*32 + t];
    if (t <= NNODE) offL[t] = csrOff[g*132 + t];
    if (t < 128) ((int4*)sbL)[t] = ((const int4*)(csrSB + (size_t)g * EPGc))[t];
    __syncthreads();

    // ---- phase 1: xp = xF @ WL -> xpL ; as/ad from folded vectors ----
    for (int p = t; p < NNODE * 32; p += 256) {
        int n = p >> 5, c = p & 31;
        const float* xr = xF + n * KIN;
        float acc = 0.f;
        #pragma unroll
        for (int k = 0; k < KIN; k++) acc = fmaf(xr[k], WL[k*32 + c], acc);
        xpL[n*36 + c] = acc;
    }
    if (t < NNODE) {
        const float* xr = xF + t * KIN;
        float s = 0.f, d = 0.f;
        #pragma unroll
        for (int k = 0; k < KIN; k++) { float v = xr[k]; s = fmaf(v, WsSL[k], s); d = fmaf(v, WsDL[k], d); }
        asL[t] = s; adL[t] = d;
    }
    __syncthreads();

    // ---- phase 2: per-node segment max (lrelu monotone => exact), wE, denominator ----
    // deterministic in CSR order; no atomics
    if (t < NNODE) {
        float as_n = asL[t], adn = adL[t];
        int lo = offL[t], hi = offL[t + 1];
        float mx = as_n;                                 // self-loop seeds max
        for (int i = lo; i < hi; i++) mx = fmaxf(mx, asL[sbL[i]]);
        float m = lrelu(mx + adn);
        float ws = expf(lrelu(as_n + adn) - m);
        float den = ws;
        for (int i = lo; i < hi; i++) {
            float w = expf(lrelu(asL[sbL[i]] + adn) - m);
            wEL[i] = w; den += w;
        }
        mM[t] = m; sfW[t] = ws; sDen[t] = den;
    }
    __syncthreads();

    // ---- phase 3: aggregation, stored wE, all LDS, conflict-free b128 gather ----
    const float4* X4 = (const float4*)xpL;
    for (int p = t; p < NNODE * 8; p += 256) {
        int n = p >> 3, c4 = p & 7;
        float w0 = sfW[n];
        float4 v = X4[n*9 + c4];
        float4 acc; acc.x = w0*v.x; acc.y = w0*v.y; acc.z = w0*v.z; acc.w = w0*v.w;
        int lo = offL[n], hi = offL[n + 1];
        for (int i = lo; i < hi; i++) {
            int sc = sbL[i]; float w = wEL[i];
            float4 u = X4[sc*9 + c4];
            acc.x = fmaf(w, u.x, acc.x); acc.y = fmaf(w, u.y, acc.y);
            acc.z = fmaf(w, u.z, acc.z); acc.w = fmaf(w, u.w, acc.w);
        }
        float inv = 1.f / (sDen[n] + 1e-16f);
        float4 r;
        r.x = fmaxf(fmaf(acc.x, inv, bL[c4*4 + 0]), 0.f);
        r.y = fmaxf(fmaf(acc.y, inv, bL[c4*4 + 1]), 0.f);
        r.z = fmaxf(fmaf(acc.z, inv, bL[c4*4 + 2]), 0.f);
        r.w = fmaxf(fmaf(acc.w, inv, bL[c4*4 + 3]), 0.f);
        *(float4*)(outp + (size_t)(g * NNODE + n) * FD + h*32 + c4*4) = r;
    }
}

// ---- linear 128->32: 32 rows/block, 4 rows/thread, W staged in LDS ----
__global__ __launch_bounds__(256) void k_lin(const float* __restrict__ in,
    const float* __restrict__ W, const float* __restrict__ b, float* __restrict__ outp)
{
    __shared__ float WtL[FD * HIDc];
    int t = threadIdx.x;
    for (int i = t; i < FD * HIDc / 4; i += 256) ((float4*)WtL)[i] = ((const float4*)W)[i];
    __syncthreads();
    int j = t & 31, rg = t >> 5;
    int r0 = blockIdx.x * 32 + rg * 4;
    const float* i0 = in + (size_t)r0 * FD;
    float bj = b[j];
    float a0 = bj, a1 = bj, a2 = bj, a3 = bj;
    for (int k4 = 0; k4 < 32; k4++) {
        float4 v0 = *(const float4*)(i0 + k4*4);
        float4 v1 = *(const float4*)(i0 + FD + k4*4);
        float4 v2 = *(const float4*)(i0 + 2*FD + k4*4);
        float4 v3 = *(const float4*)(i0 + 3*FD + k4*4);
        float w0 = WtL[(k4*4 + 0)*HIDc + j], w1 = WtL[(k4*4 + 1)*HIDc + j];
        float w2 = WtL[(k4*4 + 2)*HIDc + j], w3 = WtL[(k4*4 + 3)*HIDc + j];
        a0 = fmaf(v0.x, w0, a0); a0 = fmaf(v0.y, w1, a0); a0 = fmaf(v0.z, w2, a0); a0 = fmaf(v0.w, w3, a0);
        a1 = fmaf(v1.x, w0, a1); a1 = fmaf(v1.y, w1, a1); a1 = fmaf(v1.z, w2, a1); a1 = fmaf(v1.w, w3, a1);
        a2 = fmaf(v2.x, w0, a2); a2 = fmaf(v2.y, w1, a2); a2 = fmaf(v2.z, w2, a2); a2 = fmaf(v2.w, w3, a2);
        a3 = fmaf(v3.x, w0, a3); a3 = fmaf(v3.y, w1, a3); a3 = fmaf(v3.z, w2, a3); a3 = fmaf(v3.w, w3, a3);
    }
    size_t ob = (size_t)r0 * HIDc + j;
    outp[ob] = a0; outp[ob + 32] = a1; outp[ob + 64] = a2; outp[ob + 96] = a3;
}

// ---- top-k pool + readout, one graph per block ----
template<int NIN, int KEEP, bool FIRST>
__global__ __launch_bounds__(256) void k_pool(const float* __restrict__ ht,
    const float* __restrict__ pw, float* __restrict__ xnew, int* __restrict__ rankv,
    float* __restrict__ gfeat, const float* __restrict__ gprev)
{
    int g = blockIdx.x, t = threadIdx.x;
    __shared__ float htL[NIN * 33];
    __shared__ float scoreL[NIN], valL[NIN];
    __shared__ int rnkL[NIN];
    for (int i = t; i < NIN * 8; i += 256) {
        int n = i >> 3, q = i & 7;
        float4 v = *(const float4*)(ht + (size_t)(g*NIN + n)*HIDc + q*4);
        float* dst = htL + n*33 + q*4;
        dst[0] = v.x; dst[1] = v.y; dst[2] = v.z; dst[3] = v.w;
    }
    __syncthreads();
    float nrm; { float ss = 0.f; for (int k = 0; k < HIDc; k++) { float w = pw[k]; ss = fmaf(w, w, ss); } nrm = sqrtf(ss); }
    if (t < NIN) {
        float dot = 0.f;
        for (int k = 0; k < HIDc; k++) dot = fmaf(htL[t*33 + k], pw[k], dot);
        float val = tanhf(dot / nrm);
        scoreL[t] = val; valL[t] = val;
    }
    __syncthreads();
    if (t < NIN) {
        float si = scoreL[t]; int rank = 0;
        for (int q = 0; q < NIN; q++) {
            float sj = scoreL[q];
            rank += (sj > si || (sj == si && q < t)) ? 1 : 0;
        }
        rnkL[t] = (rank < KEEP) ? rank : -1;
        if (FIRST) rankv[g*NPGc + t] = rnkL[t];
    }
    __syncthreads();
    if (FIRST) {
        for (int p = t; p < NIN * 32; p += 256) {
            int n = p >> 5, jj = p & 31;
            int rk = rnkL[n];
            if (rk >= 0) xnew[((size_t)g*KEEP + rk)*HIDc + jj] = htL[n*33 + jj] * valL[n];
        }
    }
    if (t < HIDc) {
        float mx = -INFINITY, sm = 0.f;
        for (int n = 0; n < NIN; n++) {
            if (rnkL[n] >= 0) { float v = htL[n*33 + t] * valL[n]; mx = fmaxf(mx, v); sm += v; }
        }
        float mean = sm / (float)KEEP;
        if (FIRST) {
            gfeat[(size_t)g*64 + t]      = mx;
            gfeat[(size_t)g*64 + 32 + t] = mean;
        } else {
            gfeat[(size_t)g*64 + t]      = gprev[(size_t)g*64 + t] + mx;
            gfeat[(size_t)g*64 + 32 + t] = gprev[(size_t)g*64 + 32 + t] + mean;
        }
    }
}

// ---- MLP part A: block = (4 graphs, quarter of h2) ----
__global__ __launch_bounds__(256) void k_mlpA(const float* __restrict__ gsum,
    const float* __restrict__ W1, const float* __restrict__ b1,
    const float* __restrict__ W2, const float* __restrict__ b2,
    const float* __restrict__ W3, float* __restrict__ part)
{
    int gb = blockIdx.x, q = blockIdx.y, t = threadIdx.x;
    int g0 = gb * 4;
    __shared__ float gL[256];
    __shared__ float h1L[1024];
    __shared__ float4 red[256];
    gL[t] = gsum[(size_t)g0*64 + t];
    __syncthreads();
    float bv = b1[t];
    float a0 = bv, a1 = bv, a2 = bv, a3 = bv;
    #pragma unroll 4
    for (int k = 0; k < 64; k++) {
        float w = W1[k*256 + t];
        a0 = fmaf(gL[k], w, a0); a1 = fmaf(gL[64 + k], w, a1);
        a2 = fmaf(gL[128 + k], w, a2); a3 = fmaf(gL[192 + k], w, a3);
    }
    h1L[t] = fmaxf(a0, 0.f); h1L[256 + t] = fmaxf(a1, 0.f);
    h1L[512 + t] = fmaxf(a2, 0.f); h1L[768 + t] = fmaxf(a3, 0.f);
    __syncthreads();
    int o = q * 256 + t;
    float b2v = b2[o], w3 = W3[o];
    float c0 = b2v, c1 = b2v, c2 = b2v, c3 = b2v;
    const float* w2c = W2 + o;
    #pragma unroll 8
    for (int i = 0; i < 256; i++) {
        float w = w2c[(size_t)i * 1024];
        c0 = fmaf(h1L[i], w, c0); c1 = fmaf(h1L[256 + i], w, c1);
        c2 = fmaf(h1L[512 + i], w, c2); c3 = fmaf(h1L[768 + i], w, c3);
    }
    red[t] = make_float4(fmaxf(c0, 0.f)*w3, fmaxf(c1, 0.f)*w3, fmaxf(c2, 0.f)*w3, fmaxf(c3, 0.f)*w3);
    __syncthreads();
    for (int s = 128; s > 0; s >>= 1) {
        if (t < s) { float4 a = red[t], b = red[t + s]; a.x += b.x; a.y += b.y; a.z += b.z; a.w += b.w; red[t] = a; }
        __syncthreads();
    }
    if (t == 0) {
        float4 r = red[0];
        part[(size_t)(g0 + 0)*4 + q] = r.x;
        part[(size_t)(g0 + 1)*4 + q] = r.y;
        part[(size_t)(g0 + 2)*4 + q] = r.z;
        part[(size_t)(g0 + 3)*4 + q] = r.w;
    }
}

// ---- MLP part B: deterministic 4-way partial sum + bias ----
__global__ void k_mlpB(const float* __restrict__ part, const float* __restrict__ b3,
                       float* __restrict__ outp)
{
    int g = blockIdx.x * 256 + threadIdx.x;
    if (g < NG) {
        float4 p = ((const float4*)part)[g];
        outp[g] = ((p.x + p.y) + (p.z + p.w)) + b3[0];
    }
}

extern "C" void kernel_launch(void* const* d_in, const int* in_sizes, int n_in,
                              void* d_out, int out_size, void* d_ws, size_t ws_size,
                              hipStream_t stream)
{
    const float* x    = (const float*)d_in[0];
    const int*   ei   = (const int*)  d_in[1];
    const float* W_g1 = (const float*)d_in[4];
    const float* as1w = (const float*)d_in[5];
    const float* ad1w = (const float*)d_in[6];
    const float* b_g1 = (const float*)d_in[7];
    const float* W_t1 = (const float*)d_in[8];
    const float* b_t1 = (const float*)d_in[9];
    const float* pw1  = (const float*)d_in[10];
    const float* W_g2 = (const float*)d_in[11];
    const float* as2w = (const float*)d_in[12];
    const float* ad2w = (const float*)d_in[13];
    const float* b_g2 = (const float*)d_in[14];
    const float* W_t2 = (const float*)d_in[15];
    const float* b_t2 = (const float*)d_in[16];
    const float* pw2  = (const float*)d_in[17];
    const float* W_l1 = (const float*)d_in[18];
    const float* b_l1 = (const float*)d_in[19];
    const float* W_l2 = (const float*)d_in[20];
    const float* b_l2 = (const float*)d_in[21];
    const float* W_l3 = (const float*)d_in[22];
    const float* b_l3 = (const float*)d_in[23];
    float* out = (float*)d_out;

    char* ws = (char*)d_ws;
    size_t off = 0;
    auto alloc = [&](size_t bytes) -> void* {
        void* p = (void*)(ws + off);
        off += ((bytes + 255) / 256) * 256;
        return p;
    };
    float* hg1   = (float*)alloc((size_t)NN * FD * 4);    // reused as hg2
    float* ht1   = (float*)alloc((size_t)NN * HIDc * 4);  // reused as ht2
    float* x2    = (float*)alloc((size_t)N2c * HIDc * 4);
    int*   rank1 = (int*)  alloc((size_t)NN * 4);
    float* g1    = (float*)alloc((size_t)NG * 64 * 4);
    float* gsum  = (float*)alloc((size_t)NG * 64 * 4);
    float* part  = (float*)alloc((size_t)NG * 4 * 4);
    float* wsS1  = (float*)alloc(64 * 4);
    float* wsD1  = (float*)alloc(64 * 4);
    float* wsS2  = (float*)alloc(128 * 4);
    float* wsD2  = (float*)alloc(128 * 4);
    int*   off1  = (int*)  alloc((size_t)NG * 132 * 4);
    unsigned char* sb1 = (unsigned char*)alloc((size_t)NG * EPGc);
    int*   off2  = (int*)  alloc((size_t)NG * 132 * 4);
    unsigned char* sb2 = (unsigned char*)alloc((size_t)NG * EPGc);
    float* hg2 = hg1;
    float* ht2 = ht1;

    k_fold2<<<2, 128, 0, stream>>>(W_g1, as1w, ad1w, wsS1, wsD1,
                                   W_g2, as2w, ad2w, wsS2, wsD2);
    k_csr<false><<<NG, 256, 0, stream>>>(ei, nullptr, off1, sb1, NPGc);

    k_gat<NPGc, IND><<<dim3(NG, 4), 256, 0, stream>>>(
        x, W_g1, wsS1, wsD1, off1, sb1, b_g1, hg1);
    k_lin<<<NN/32, 256, 0, stream>>>(hg1, W_t1, b_t1, ht1);
    k_pool<NPGc, K1c, true><<<NG, 256, 0, stream>>>(
        ht1, pw1, x2, rank1, g1, nullptr);

    k_csr<true><<<NG, 256, 0, stream>>>(ei, rank1, off2, sb2, K1c);
    k_gat<K1c, HIDc><<<dim3(NG, 4), 256, 0, stream>>>(
        x2, W_g2, wsS2, wsD2, off2, sb2, b_g2, hg2);
    k_lin<<<N2c/32, 256, 0, stream>>>(hg2, W_t2, b_t2, ht2);
    k_pool<K1c, K2c, false><<<NG, 256, 0, stream>>>(
        ht2, pw2, nullptr, nullptr, gsum, g1);

    k_mlpA<<<dim3(NG/4, 4), 256, 0, stream>>>(gsum, W_l1, b_l1, W_l2, b_l2, W_l3, part);
    k_mlpB<<<2, 256, 0, stream>>>(part, b_l3, out);
}

// Round 7
// 315.196 us; speedup vs baseline: 1.1582x; 1.0450x over previous
//
#include <hip/hip_runtime.h>
#include <math.h>

constexpr int NPGc  = 128;     // nodes per graph (layer 1)
constexpr int NG    = 512;     // graphs
constexpr int EPGc  = 2048;    // edges per graph
constexpr int ETOT  = 1048576; // total edges
constexpr int IND   = 11;
constexpr int HIDc  = 32;
constexpr int FD    = 128;     // HEADS*HID
constexpr int K1c   = 103;
constexpr int K2c   = 83;
constexpr int NN    = NG * NPGc;
constexpr int N2c   = NG * K1c;

__device__ __forceinline__ float lrelu(float x){ return fmaxf(x, 0.2f*x); }

// order-preserving float<->uint for atomicMax (max is order-invariant => exact)
__device__ __forceinline__ unsigned flipF(float f){
    unsigned u = __float_as_uint(f);
    return u ^ (unsigned)(((int)u >> 31) | 0x80000000);
}
__device__ __forceinline__ float unflipF(unsigned u){
    unsigned m = ((u >> 31) - 1u) | 0x80000000u;
    return __uint_as_float(u ^ m);
}

// ---- fold attention vectors through Wg: Ws[k][h] = sum_j Wg[k][h*32+j]*av[h*32+j]
template<int KIN>
__device__ void foldDev(const float* __restrict__ Wg, const float* __restrict__ avs,
                        const float* __restrict__ avd, float* __restrict__ S, float* __restrict__ D, int t)
{
    if (t < KIN * 4) {
        int k = t >> 2, h = t & 3;
        float s = 0.f, d = 0.f;
        for (int j = 0; j < HIDc; j++) {
            float w = Wg[k*FD + h*HIDc + j];
            s = fmaf(w, avs[h*HIDc + j], s);
            d = fmaf(w, avd[h*HIDc + j], d);
        }
        S[t] = s; D[t] = d;
    }
}
__global__ void k_fold2(const float* W1, const float* s1, const float* d1, float* S1, float* D1,
                        const float* W2, const float* s2, const float* d2, float* S2, float* D2)
{
    if (blockIdx.x == 0) foldDev<IND>(W1, s1, d1, S1, D1, threadIdx.x);
    else                 foldDev<HIDc>(W2, s2, d2, S2, D2, threadIdx.x);
}

// ---- CSR build, once per graph (head-independent); stores src AND dst per slot ----
template<bool REMAP>
__global__ __launch_bounds__(256) void k_csr(const int* __restrict__ ei, const int* __restrict__ rankv,
                                             int* __restrict__ csrOff, unsigned char* __restrict__ csrSB,
                                             unsigned char* __restrict__ csrDB, int nnode)
{
    int g = blockIdx.x, t = threadIdx.x;
    __shared__ int cnt[128], cur[128], offL[129];
    __shared__ unsigned char sbL[EPGc], dbL[EPGc];
    __shared__ signed char rmap[NPGc];
    if (t < 128) cnt[t] = 0;
    if constexpr (REMAP) { if (t < NPGc) rmap[t] = (signed char)rankv[g*NPGc + t]; }
    __syncthreads();
    const int* dstG = ei + ETOT + g * EPGc;
    int sn[8], dn[8];
    #pragma unroll
    for (int q = 0; q < 8; q++) {
        int e = t + 256*q;
        int dO = dstG[e] - g * NPGc, s0 = e >> 4;    // src is structural: e/16
        if constexpr (REMAP) {
            int s = rmap[s0], d = rmap[dO];
            bool ok = (s >= 0 && d >= 0);
            sn[q] = s; dn[q] = ok ? d : -1;
        } else { sn[q] = s0; dn[q] = dO; }
        if (dn[q] >= 0) atomicAdd(&cnt[dn[q]], 1);
    }
    __syncthreads();
    if (t < 64) {
        int c0 = cnt[2*t], c1 = cnt[2*t + 1], ps = c0 + c1, P = ps;
        #pragma unroll
        for (int dlt = 1; dlt < 64; dlt <<= 1) { int v = __shfl_up(P, dlt); if (t >= dlt) P += v; }
        int E0 = P - ps;
        offL[2*t] = E0; offL[2*t + 1] = E0 + c0;
        cur[2*t] = E0; cur[2*t + 1] = E0 + c0;
        if (t == 63) offL[128] = P;
    }
    __syncthreads();
    #pragma unroll
    for (int q = 0; q < 8; q++) {
        if (dn[q] >= 0) {
            int pos = atomicAdd(&cur[dn[q]], 1);
            sbL[pos] = (unsigned char)sn[q];
            dbL[pos] = (unsigned char)dn[q];
        }
    }
    __syncthreads();
    if (t < 128) {
        ((int4*)(csrSB + (size_t)g * EPGc))[t] = ((const int4*)sbL)[t];
        ((int4*)(csrDB + (size_t)g * EPGc))[t] = ((const int4*)dbL)[t];
    }
    if (t <= nnode) csrOff[g*132 + t] = offL[t];
}

// ---- fused layer: proj + GAT(4 heads) + W_t linear + topk pool + readout ----
// one block per graph; 512 blocks = 2/CU fully resident
template<int NNODE, int KIN, int KEEP, bool FIRST>
__global__ __launch_bounds__(256, 4) void k_layer(
    const float* __restrict__ xin, const float* __restrict__ Wg,
    const float* __restrict__ WsS, const float* __restrict__ WsD,
    const float* __restrict__ bg,
    const float* __restrict__ Wt, const float* __restrict__ bt,
    const float* __restrict__ pw,
    const int* __restrict__ csrOff, const unsigned char* __restrict__ csrSB,
    const unsigned char* __restrict__ csrDB,
    float* __restrict__ xnew, int* __restrict__ rankv,
    float* __restrict__ gfeat, const float* __restrict__ gprev)
{
    constexpr int NP   = (NNODE + 3) & ~3;   // node count padded to mult of 4
    constexpr int NGRP = NP / 4;
    int g = blockIdx.x, t = threadIdx.x;

    __shared__ __align__(16) float xFT[KIN * NP];     // transposed input [k][n]
    __shared__ __align__(16) float WfL[KIN * FD];
    __shared__ __align__(16) float WtL[FD * HIDc];
    __shared__ __align__(16) float xpL[NP * 36];      // proj / relu slice; later htL
    __shared__ float wEu[EPGc];                       // edge weights; later pool arrays
    __shared__ unsigned char sbL[EPGc], dbL[EPGc];
    __shared__ int offL[NNODE + 1];
    __shared__ float asL[NNODE], adL[NNODE], sfW[NNODE], sDi[NNODE];
    __shared__ unsigned maxU[NNODE];
    __shared__ __align__(8) float admL[NNODE * 2];
    __shared__ float WsSL[KIN * 4], WsDL[KIN * 4], bgL[FD], btL[HIDc];

    // ---- stage everything once ----
    {
        const float* xg = xin + (size_t)g * NNODE * KIN;
        for (int i = t; i < NNODE * KIN; i += 256) {
            int n = i / KIN, k = i - n * KIN;
            xFT[k * NP + n] = xg[i];
        }
        if constexpr (NP > NNODE) {
            for (int i = t; i < KIN * (NP - NNODE); i += 256) {
                int k = i / (NP - NNODE), n = NNODE + (i % (NP - NNODE));
                xFT[k * NP + n] = 0.f;                // zero pad cols -> pad rows stay 0
            }
        }
    }
    for (int i = t; i < KIN * FD / 4; i += 256) ((float4*)WfL)[i] = ((const float4*)Wg)[i];
    for (int i = t; i < FD * HIDc / 4; i += 256) ((float4*)WtL)[i] = ((const float4*)Wt)[i];
    for (int i = t; i < KIN * 4; i += 256) { WsSL[i] = WsS[i]; WsDL[i] = WsD[i]; }
    if (t < FD) bgL[t] = bg[t];
    if (t < HIDc) btL[t] = bt[t];
    if (t <= NNODE) offL[t] = csrOff[g*132 + t];
    for (int i = t; i < EPGc / 16; i += 256) {
        ((int4*)sbL)[i] = ((const int4*)(csrSB + (size_t)g * EPGc))[i];
        ((int4*)dbL)[i] = ((const int4*)(csrDB + (size_t)g * EPGc))[i];
    }
    __syncthreads();
    const int EC = offL[NNODE];

    // W_t accumulators: thread owns (4 nodes, 4 out-channels); live across heads
    const int n4 = t >> 3, j4 = t & 7;
    float4 acc0, acc1, acc2, acc3;
    { float4 bi = make_float4(btL[j4*4], btL[j4*4+1], btL[j4*4+2], btL[j4*4+3]);
      acc0 = bi; acc1 = bi; acc2 = bi; acc3 = bi; }

    for (int h = 0; h < 4; h++) {
        __syncthreads();   // xpL free (prev head's lin reads done)

        // proj: xpL[n][c] = sum_k xFT[k][n] * W[k][h*32+c]  (x as b128, 4 nodes/lane)
        for (int id = t; id < NGRP * 32; id += 256) {
            int grp = id >> 5, c = id & 31;
            float4 a = make_float4(0.f, 0.f, 0.f, 0.f);
            #pragma unroll
            for (int k = 0; k < KIN; k++) {
                float4 xv = *(const float4*)&xFT[k * NP + grp * 4];
                float w = WfL[k * FD + h * 32 + c];
                a.x = fmaf(xv.x, w, a.x); a.y = fmaf(xv.y, w, a.y);
                a.z = fmaf(xv.z, w, a.z); a.w = fmaf(xv.w, w, a.w);
            }
            int nb = grp * 4;
            xpL[(nb+0)*36 + c] = a.x; xpL[(nb+1)*36 + c] = a.y;
            xpL[(nb+2)*36 + c] = a.z; xpL[(nb+3)*36 + c] = a.w;
        }
        // att dots via folded vectors; self seeds the max
        if (t < NNODE) {
            float s = 0.f, d = 0.f;
            #pragma unroll
            for (int k = 0; k < KIN; k++) {
                float v = xFT[k * NP + t];
                s = fmaf(v, WsSL[k*4 + h], s);
                d = fmaf(v, WsDL[k*4 + h], d);
            }
            asL[t] = s; adL[t] = d; maxU[t] = flipF(s);
        }
        __syncthreads();

        // slot-parallel exact per-dst max of as (lrelu monotone)
        for (int s = t; s < EC; s += 256)
            atomicMax(&maxU[dbL[s]], flipF(asL[sbL[s]]));
        __syncthreads();

        // node: m, self weight
        if (t < NNODE) {
            float ad = adL[t];
            float m = lrelu(unflipF(maxU[t]) + ad);
            admL[2*t] = ad; admL[2*t + 1] = m;
            sfW[t] = expf(lrelu(asL[t] + ad) - m);
        }
        __syncthreads();

        // slot-parallel edge weights (contiguous writes)
        for (int s = t; s < EC; s += 256) {
            int sb = sbL[s], db = dbL[s];
            float2 am = *(const float2*)&admL[2*db];
            wEu[s] = expf(lrelu(asL[sb] + am.x) - am.y);
        }
        __syncthreads();

        // deterministic denominator in CSR order -> inverse
        if (t < NNODE) {
            float den = sfW[t];
            int lo = offL[t], hi = offL[t + 1];
            for (int s = lo; s < hi; s++) den += wEu[s];
            sDi[t] = 1.f / (den + 1e-16f);
        }
        __syncthreads();

        // aggregation (item = node, float4 chunk) into registers
        const float4* X4 = (const float4*)xpL;
        auto aggOne = [&](int p) -> float4 {
            int n = p >> 3, c4 = p & 7;
            float w0 = sfW[n];
            float4 v = X4[n*9 + c4];
            float4 a; a.x = w0*v.x; a.y = w0*v.y; a.z = w0*v.z; a.w = w0*v.w;
            int lo = offL[n], hi = offL[n + 1];
            for (int s = lo; s < hi; s++) {
                int sc = sbL[s]; float w = wEu[s];
                float4 u = X4[sc*9 + c4];
                a.x = fmaf(w, u.x, a.x); a.y = fmaf(w, u.y, a.y);
                a.z = fmaf(w, u.z, a.z); a.w = fmaf(w, u.w, a.w);
            }
            float inv = sDi[n];
            float4 r;
            r.x = fmaxf(fmaf(a.x, inv, bgL[h*32 + c4*4 + 0]), 0.f);
            r.y = fmaxf(fmaf(a.y, inv, bgL[h*32 + c4*4 + 1]), 0.f);
            r.z = fmaxf(fmaf(a.z, inv, bgL[h*32 + c4*4 + 2]), 0.f);
            r.w = fmaxf(fmaf(a.w, inv, bgL[h*32 + c4*4 + 3]), 0.f);
            return r;
        };
        float4 rv0 = aggOne(t);
        float4 rv1 = aggOne(t + 256);
        float4 rv2 = aggOne(t + 512);
        float4 rv3;
        if (t + 768 < NNODE * 8) rv3 = aggOne(t + 768);
        __syncthreads();   // all agg reads of xpL done

        // write relu slice back into xpL (in place)
        float4* X4w = (float4*)xpL;
        X4w[(t>>3)*9 + (t&7)] = rv0;
        { int p = t + 256; X4w[(p>>3)*9 + (p&7)] = rv1; }
        { int p = t + 512; X4w[(p>>3)*9 + (p&7)] = rv2; }
        if (t + 768 < NNODE * 8) { int p = t + 768; X4w[(p>>3)*9 + (p&7)] = rv3; }
        __syncthreads();

        // W_t accumulate: acc[n4..+3][j4*4..+3] += relu @ Wt[h*32..]
        if (n4 < NGRP) {
            int nb = n4 * 4;
            #pragma unroll 8
            for (int c = 0; c < 32; c++) {
                float4 w4 = *(const float4*)&WtL[(h*32 + c)*HIDc + j4*4];
                float r0 = xpL[(nb+0)*36 + c], r1 = xpL[(nb+1)*36 + c];
                float r2 = xpL[(nb+2)*36 + c], r3 = xpL[(nb+3)*36 + c];
                acc0.x = fmaf(r0, w4.x, acc0.x); acc0.y = fmaf(r0, w4.y, acc0.y);
                acc0.z = fmaf(r0, w4.z, acc0.z); acc0.w = fmaf(r0, w4.w, acc0.w);
                acc1.x = fmaf(r1, w4.x, acc1.x); acc1.y = fmaf(r1, w4.y, acc1.y);
                acc1.z = fmaf(r1, w4.z, acc1.z); acc1.w = fmaf(r1, w4.w, acc1.w);
                acc2.x = fmaf(r2, w4.x, acc2.x); acc2.y = fmaf(r2, w4.y, acc2.y);
                acc2.z = fmaf(r2, w4.z, acc2.z); acc2.w = fmaf(r2, w4.w, acc2.w);
                acc3.x = fmaf(r3, w4.x, acc3.x); acc3.y = fmaf(r3, w4.y, acc3.y);
                acc3.z = fmaf(r3, w4.z, acc3.z); acc3.w = fmaf(r3, w4.w, acc3.w);
            }
        }
    }
    __syncthreads();   // last lin reads done; xpL region becomes htL

    // ht rows into LDS (row stride 33)
    float* htL = xpL;
    if (n4 < NGRP) {
        int nb = n4 * 4, jb = j4 * 4;
        float4 av[4] = {acc0, acc1, acc2, acc3};
        #pragma unroll
        for (int i = 0; i < 4; i++) {
            int n = nb + i;
            if (n < NNODE) {
                htL[n*33 + jb + 0] = av[i].x; htL[n*33 + jb + 1] = av[i].y;
                htL[n*33 + jb + 2] = av[i].z; htL[n*33 + jb + 3] = av[i].w;
            }
        }
    }
    __syncthreads();

    // top-k pool + readout (score/rank arrays alias wEu)
    float* scoreL = wEu;
    int*   rnkL   = (int*)(wEu + 128);
    float nrm; { float ss = 0.f; for (int k = 0; k < HIDc; k++) { float w = pw[k]; ss = fmaf(w, w, ss); } nrm = sqrtf(ss); }
    if (t < NNODE) {
        float dot = 0.f;
        for (int k = 0; k < HIDc; k++) dot = fmaf(htL[t*33 + k], pw[k], dot);
        scoreL[t] = tanhf(dot / nrm);
    }
    __syncthreads();
    if (t < NNODE) {
        float si = scoreL[t]; int rank = 0;
        for (int q = 0; q < NNODE; q++) {
            float sj = scoreL[q];
            rank += (sj > si || (sj == si && q < t)) ? 1 : 0;
        }
        rnkL[t] = (rank < KEEP) ? rank : -1;
        if (FIRST) rankv[g*NPGc + t] = rnkL[t];
    }
    __syncthreads();
    if (FIRST) {
        for (int p = t; p < NNODE * 32; p += 256) {
            int n = p >> 5, jj = p & 31;
            int rk = rnkL[n];
            if (rk >= 0) xnew[((size_t)g*KEEP + rk)*HIDc + jj] = htL[n*33 + jj] * scoreL[n];
        }
    }
    if (t < HIDc) {
        float mx = -INFINITY, sm = 0.f;
        for (int n = 0; n < NNODE; n++) {
            if (rnkL[n] >= 0) { float v = htL[n*33 + t] * scoreL[n]; mx = fmaxf(mx, v); sm += v; }
        }
        float mean = sm / (float)KEEP;
        if (FIRST) {
            gfeat[(size_t)g*64 + t]      = mx;
            gfeat[(size_t)g*64 + 32 + t] = mean;
        } else {
            gfeat[(size_t)g*64 + t]      = gprev[(size_t)g*64 + t] + mx;
            gfeat[(size_t)g*64 + 32 + t] = gprev[(size_t)g*64 + 32 + t] + mean;
        }
    }
}

// ---- MLP part A: block = (4 graphs, quarter of h2) ----
__global__ __launch_bounds__(256) void k_mlpA(const float* __restrict__ gsum,
    const float* __restrict__ W1, const float* __restrict__ b1,
    const float* __restrict__ W2, const float* __restrict__ b2,
    const float* __restrict__ W3, float* __restrict__ part)
{
    int gb = blockIdx.x, q = blockIdx.y, t = threadIdx.x;
    int g0 = gb * 4;
    __shared__ float gL[256];
    __shared__ float h1L[1024];
    __shared__ float4 red[256];
    gL[t] = gsum[(size_t)g0*64 + t];
    __syncthreads();
    float bv = b1[t];
    float a0 = bv, a1 = bv, a2 = bv, a3 = bv;
    #pragma unroll 4
    for (int k = 0; k < 64; k++) {
        float w = W1[k*256 + t];
        a0 = fmaf(gL[k], w, a0); a1 = fmaf(gL[64 + k], w, a1);
        a2 = fmaf(gL[128 + k], w, a2); a3 = fmaf(gL[192 + k], w, a3);
    }
    h1L[t] = fmaxf(a0, 0.f); h1L[256 + t] = fmaxf(a1, 0.f);
    h1L[512 + t] = fmaxf(a2, 0.f); h1L[768 + t] = fmaxf(a3, 0.f);
    __syncthreads();
    int o = q * 256 + t;
    float b2v = b2[o], w3 = W3[o];
    float c0 = b2v, c1 = b2v, c2 = b2v, c3 = b2v;
    const float* w2c = W2 + o;
    #pragma unroll 8
    for (int i = 0; i < 256; i++) {
        float w = w2c[(size_t)i * 1024];
        c0 = fmaf(h1L[i], w, c0); c1 = fmaf(h1L[256 + i], w, c1);
        c2 = fmaf(h1L[512 + i], w, c2); c3 = fmaf(h1L[768 + i], w, c3);
    }
    red[t] = make_float4(fmaxf(c0, 0.f)*w3, fmaxf(c1, 0.f)*w3, fmaxf(c2, 0.f)*w3, fmaxf(c3, 0.f)*w3);
    __syncthreads();
    for (int s = 128; s > 0; s >>= 1) {
        if (t < s) { float4 a = red[t], b = red[t + s]; a.x += b.x; a.y += b.y; a.z += b.z; a.w += b.w; red[t] = a; }
        __syncthreads();
    }
    if (t == 0) {
        float4 r = red[0];
        part[(size_t)(g0 + 0)*4 + q] = r.x;
        part[(size_t)(g0 + 1)*4 + q] = r.y;
        part[(size_t)(g0 + 2)*4 + q] = r.z;
        part[(size_t)(g0 + 3)*4 + q] = r.w;
    }
}

// ---- MLP part B: deterministic 4-way partial sum + bias ----
__global__ void k_mlpB(const float* __restrict__ part, const float* __restrict__ b3,
                       float* __restrict__ outp)
{
    int g = blockIdx.x * 256 + threadIdx.x;
    if (g < NG) {
        float4 p = ((const float4*)part)[g];
        outp[g] = ((p.x + p.y) + (p.z + p.w)) + b3[0];
    }
}

extern "C" void kernel_launch(void* const* d_in, const int* in_sizes, int n_in,
                              void* d_out, int out_size, void* d_ws, size_t ws_size,
                              hipStream_t stream)
{
    const float* x    = (const float*)d_in[0];
    const int*   ei   = (const int*)  d_in[1];
    const float* W_g1 = (const float*)d_in[4];
    const float* as1w = (const float*)d_in[5];
    const float* ad1w = (const float*)d_in[6];
    const float* b_g1 = (const float*)d_in[7];
    const float* W_t1 = (const float*)d_in[8];
    const float* b_t1 = (const float*)d_in[9];
    const float* pw1  = (const float*)d_in[10];
    const float* W_g2 = (const float*)d_in[11];
    const float* as2w = (const float*)d_in[12];
    const float* ad2w = (const float*)d_in[13];
    const float* b_g2 = (const float*)d_in[14];
    const float* W_t2 = (const float*)d_in[15];
    const float* b_t2 = (const float*)d_in[16];
    const float* pw2  = (const float*)d_in[17];
    const float* W_l1 = (const float*)d_in[18];
    const float* b_l1 = (const float*)d_in[19];
    const float* W_l2 = (const float*)d_in[20];
    const float* b_l2 = (const float*)d_in[21];
    const float* W_l3 = (const float*)d_in[22];
    const float* b_l3 = (const float*)d_in[23];
    float* out = (float*)d_out;

    char* ws = (char*)d_ws;
    size_t off = 0;
    auto alloc = [&](size_t bytes) -> void* {
        void* p = (void*)(ws + off);
        off += ((bytes + 255) / 256) * 256;
        return p;
    };
    float* x2    = (float*)alloc((size_t)N2c * HIDc * 4);
    int*   rank1 = (int*)  alloc((size_t)NN * 4);
    float* g1    = (float*)alloc((size_t)NG * 64 * 4);
    float* gsum  = (float*)alloc((size_t)NG * 64 * 4);
    float* part  = (float*)alloc((size_t)NG * 4 * 4);
    float* wsS1  = (float*)alloc(64 * 4);
    float* wsD1  = (float*)alloc(64 * 4);
    float* wsS2  = (float*)alloc(128 * 4);
    float* wsD2  = (float*)alloc(128 * 4);
    int*   off1  = (int*)  alloc((size_t)NG * 132 * 4);
    unsigned char* sb1 = (unsigned char*)alloc((size_t)NG * EPGc);
    unsigned char* db1 = (unsigned char*)alloc((size_t)NG * EPGc);
    int*   off2  = (int*)  alloc((size_t)NG * 132 * 4);
    unsigned char* sb2 = (unsigned char*)alloc((size_t)NG * EPGc);
    unsigned char* db2 = (unsigned char*)alloc((size_t)NG * EPGc);

    k_fold2<<<2, 128, 0, stream>>>(W_g1, as1w, ad1w, wsS1, wsD1,
                                   W_g2, as2w, ad2w, wsS2, wsD2);
    k_csr<false><<<NG, 256, 0, stream>>>(ei, nullptr, off1, sb1, db1, NPGc);

    k_layer<NPGc, IND, K1c, true><<<NG, 256, 0, stream>>>(
        x, W_g1, wsS1, wsD1, b_g1, W_t1, b_t1, pw1,
        off1, sb1, db1, x2, rank1, g1, nullptr);

    k_csr<true><<<NG, 256, 0, stream>>>(ei, rank1, off2, sb2, db2, K1c);

    k_layer<K1c, HIDc, K2c, false><<<NG, 256, 0, stream>>>(
        x2, W_g2, wsS2, wsD2, b_g2, W_t2, b_t2, pw2,
        off2, sb2, db2, nullptr, nullptr, gsum, g1);

    k_mlpA<<<dim3(NG/4, 4), 256, 0, stream>>>(gsum, W_l1, b_l1, W_l2, b_l2, W_l3, part);
    k_mlpB<<<2, 256, 0, stream>>>(part, b_l3, out);
}